// Round 8
// baseline (538.166 us; speedup 1.0000x reference)
//
#include <hip/hip_runtime.h>
#include <math.h>

namespace {

constexpr int Bb = 4, Ss = 256, Dd = 768, Vv = 50257;
constexpr int Mm = Bb * Ss;               // 1024 rows
constexpr int BM = 128, BN = 128, BK = 32;
constexpr int NS = Dd / BK;               // 24 k-steps
constexpr int TW = (Vv + BN - 1) / BN;    // 393 W tiles (last padded w/ zeros)
constexpr int TA = Mm / BM;               // 8 A tiles
constexpr int NT8 = TW * 8;               // 3144 per-row partial slices (16 cols each)
constexpr int CHUNK = BM * BK;            // 4096 f16 = 8 KB per (tile, step) per plane
constexpr float SC = 14.4269504088896341f;   // 10 * log2(e)

typedef _Float16 f16x8 __attribute__((ext_vector_type(8)));
typedef float f32x4 __attribute__((ext_vector_type(4)));

// Packed scratch layout (inside out3 region; finalize's one-hot overwrites it
// LAST — nothing reads scratch after finalize starts):
//   Whp, Wlp, Ahp, Alp, tsq[Vv], asq[Mm], pmax[Mm*NT8], pidx[Mm*NT8], psum[Mm*NT8]
constexpr size_t WPLANE = (size_t)TW * NS * CHUNK;   // 38,633,472 f16
constexpr size_t APLANE = (size_t)TA * NS * CHUNK;   //    786,432 f16
// bytes: 2*(WPLANE+APLANE)*2 + (Vv+Mm)*4 + 3*Mm*NT8*4 = ~196.5 MB < 205.8 MB

__device__ __forceinline__ void gload_lds16(const void* g, void* l) {
    typedef __attribute__((address_space(3))) void lds_t;
    typedef const __attribute__((address_space(1))) void gm_t;
    __builtin_amdgcn_global_load_lds((gm_t*)g, (lds_t*)l, 16, 0, 0);
}

// ---------------------------------------------------------------------------
// Kernel 1: fused split-convert + pack + row-sumsq, fully-coalesced stores.
// grid (ntiles, 2): blockIdx.y = 12-step half. Waves: (wid&1) = row half
// (lane -> row, so each plane store is a 1 KB contiguous wave burst),
// (wid>>1) = 6-step sub-half. Row sumsq: block partial + atomicAdd
// (sumsq pre-zeroed by hipMemsetAsync). Rows >= nrows pack as zeros.
// ---------------------------------------------------------------------------
__global__ __launch_bounds__(256) void convert_pack_tsq(const float* __restrict__ src,
                                                        _Float16* __restrict__ hp,
                                                        _Float16* __restrict__ lp,
                                                        float* __restrict__ sumsq,
                                                        int nrows) {
    const int t    = blockIdx.x;
    const int tid  = threadIdx.x;
    const int wid  = tid >> 6;
    const int lane = tid & 63;
    const int r    = (wid & 1) * 64 + lane;          // 0..127 tile row
    const int s0   = blockIdx.y * 12 + (wid >> 1) * 6;
    const int v    = t * BM + r;
    const bool valid = v < nrows;

    __shared__ float sq_lds[2][128];

    float sq = 0.f;
#pragma unroll
    for (int i = 0; i < 6; ++i) {
        const int s = s0 + i;
        float vals[32];
        if (valid) {
            const float4* p = reinterpret_cast<const float4*>(src + (size_t)v * Dd + s * BK);
#pragma unroll
            for (int k = 0; k < 8; ++k) *reinterpret_cast<float4*>(&vals[4 * k]) = p[k];
        } else {
#pragma unroll
            for (int k = 0; k < 32; ++k) vals[k] = 0.f;
        }
        const size_t chunk = ((size_t)t * NS + s) * CHUNK;
#pragma unroll
        for (int fq = 0; fq < 4; ++fq) {
            _Float16 hi8[8], lo8[8];
#pragma unroll
            for (int e = 0; e < 8; ++e) {
                const float x = vals[fq * 8 + e];
                sq = fmaf(x, x, sq);
                const _Float16 h = (_Float16)x;
                hi8[e] = h;
                lo8[e] = (_Float16)(x - (float)h);
            }
            *reinterpret_cast<f16x8*>(&hp[chunk + fq * (BM * 8) + (size_t)r * 8]) =
                *reinterpret_cast<const f16x8*>(hi8);
            *reinterpret_cast<f16x8*>(&lp[chunk + fq * (BM * 8) + (size_t)r * 8]) =
                *reinterpret_cast<const f16x8*>(lo8);
        }
    }
    sq_lds[wid >> 1][r] = sq;
    __syncthreads();
    if (tid < 128) {
        const int vv = t * BM + tid;
        if (vv < nrows) atomicAdd(&sumsq[vv], sq_lds[0][tid] + sq_lds[1][tid]);
    }
}

// ---------------------------------------------------------------------------
// Kernel 2: scores = 2*(A.W^T) - tsq, packed split-f16 MFMA + XCD-chunked map.
// K-loop identical to R5 (250 us verified). Epilogue: score stores + depth-2
// shfl pre-merge (fr groups of 4) -> 4 partials per 64-col slice written
// DIRECTLY to global. No partial LDS -> SMEM 32 KB -> 5 blocks/CU.
// ---------------------------------------------------------------------------
__global__ __launch_bounds__(256) void gemm_kernel(const _Float16* __restrict__ Ahp,
                                                   const _Float16* __restrict__ Alp,
                                                   const _Float16* __restrict__ Whp,
                                                   const _Float16* __restrict__ Wlp,
                                                   const float* __restrict__ tsq,
                                                   float* __restrict__ scores,
                                                   float* __restrict__ pmax,
                                                   int*   __restrict__ pidx,
                                                   float* __restrict__ psum) {
    __shared__ _Float16 lds[4][CHUNK];     // 0:Ah 1:Al 2:Wh 3:Wl  (32 KB)

    const int b    = blockIdx.x;
    const int xcd  = b & 7;
    const int slot = b >> 3;
    const int tn   = xcd * 50 + (slot >> 3);   // contiguous tn chunk per XCD
    const int tm   = slot & 7;
    if (tn >= TW) return;

    const int tid  = threadIdx.x;
    const int wid  = tid >> 6;
    const int lane = tid & 63;
    const int wr   = wid >> 1;             // wave row (0..1)
    const int wc   = wid & 1;              // wave col (0..1)
    const int fr   = lane & 15;
    const int fq   = lane >> 4;

    const _Float16* gA_h = Ahp + (size_t)tm * NS * CHUNK;
    const _Float16* gA_l = Alp + (size_t)tm * NS * CHUNK;
    const _Float16* gW_h = Whp + (size_t)tn * NS * CHUNK;
    const _Float16* gW_l = Wlp + (size_t)tn * NS * CHUNK;

    f32x4 acc[4][4];
#pragma unroll
    for (int m = 0; m < 4; ++m)
#pragma unroll
        for (int n = 0; n < 4; ++n) acc[m][n] = (f32x4){0.f, 0.f, 0.f, 0.f};

    for (int s = 0; s < NS; ++s) {
        if (s) __syncthreads();
        const size_t so = (size_t)s * CHUNK;
        const _Float16* gsrc[4] = {gA_h + so, gA_l + so, gW_h + so, gW_l + so};
#pragma unroll
        for (int c = 0; c < 4; ++c) {
#pragma unroll
            for (int i = 0; i < 2; ++i) {
                const int seg = wid * 2 + i;              // 0..7, wave-uniform
                gload_lds16(gsrc[c] + seg * 512 + lane * 8, &lds[c][seg * 512]);
            }
        }
        __syncthreads();

        f16x8 ah[4], al[4];
#pragma unroll
        for (int m = 0; m < 4; ++m) {
            const int r = wr * 64 + m * 16 + fr;
            ah[m] = *reinterpret_cast<const f16x8*>(&lds[0][fq * (BM * 8) + r * 8]);
            al[m] = *reinterpret_cast<const f16x8*>(&lds[1][fq * (BM * 8) + r * 8]);
        }
#pragma unroll
        for (int n = 0; n < 4; ++n) {
            const int c = wc * 64 + n * 16 + fr;
            const f16x8 wh = *reinterpret_cast<const f16x8*>(&lds[2][fq * (BM * 8) + c * 8]);
            const f16x8 wl = *reinterpret_cast<const f16x8*>(&lds[3][fq * (BM * 8) + c * 8]);
#pragma unroll
            for (int m = 0; m < 4; ++m) {
                acc[m][n] = __builtin_amdgcn_mfma_f32_16x16x32_f16(ah[m], wh, acc[m][n], 0, 0, 0);
                acc[m][n] = __builtin_amdgcn_mfma_f32_16x16x32_f16(al[m], wh, acc[m][n], 0, 0, 0);
                acc[m][n] = __builtin_amdgcn_mfma_f32_16x16x32_f16(ah[m], wl, acc[m][n], 0, 0, 0);
            }
        }
    }

    // ------ epilogue: score stores + depth-2 shfl partials (no LDS) ------
    float tq[4];
    int   gcol[4];
    bool  ok[4];
#pragma unroll
    for (int n = 0; n < 4; ++n) {
        gcol[n] = tn * BN + wc * 64 + n * 16 + fr;
        ok[n]   = gcol[n] < Vv;
        tq[n]   = ok[n] ? tsq[gcol[n]] : 0.f;
    }

#pragma unroll
    for (int m = 0; m < 4; ++m) {
#pragma unroll
        for (int r = 0; r < 4; ++r) {
            const int rloc = wr * 64 + m * 16 + fq * 4 + r;
            const int grow = tm * BM + rloc;
            float sv[4];
            float vmax = -INFINITY;
            int   vidx = 0x7fffffff;
#pragma unroll
            for (int n = 0; n < 4; ++n) {
                sv[n] = ok[n] ? fmaf(2.f, acc[m][n][r], -tq[n]) : -INFINITY;
                if (ok[n]) {
                    scores[(size_t)grow * Vv + gcol[n]] = sv[n];
                    if (sv[n] > vmax) { vmax = sv[n]; vidx = gcol[n]; }  // ascending gn
                }
            }
            float ls = 0.f;
            if (vmax > -INFINITY) {
#pragma unroll
                for (int n = 0; n < 4; ++n)
                    if (ok[n]) ls += exp2f((sv[n] - vmax) * SC);
            }
            // merge across fr^1, fr^2 (depth-2 chains, independent over m,r)
#pragma unroll
            for (int off = 1; off <= 2; off <<= 1) {
                const float om = __shfl_xor(vmax, off);
                const int   oi = __shfl_xor(vidx, off);
                const float os = __shfl_xor(ls,  off);
                if (om > vmax || (om == vmax && om > -INFINITY && oi < vidx)) {
                    ls = ((vmax > -INFINITY) ? ls * exp2f((vmax - om) * SC) : 0.f) + os;
                    vmax = om; vidx = oi;
                } else if (om > -INFINITY) {
                    ls += os * exp2f((om - vmax) * SC);
                }
            }
            if ((fr & 3) == 0) {
                const int cidx = (tn * 2 + wc) * 4 + (fr >> 2);
                const size_t o = (size_t)grow * NT8 + cidx;
                pmax[o] = vmax;
                pidx[o] = vidx;
                psum[o] = ls;
            }
        }
    }
}

// ---------------------------------------------------------------------------
// Kernel 2b: merge 3144 partials per row -> pred (out2), (gmax, inv) stashed
// in the tail of out1's row (stash pattern verified in R6/R7).
// ---------------------------------------------------------------------------
__global__ __launch_bounds__(256) void reduce_stats(const float* __restrict__ pmax,
                                                    const int*   __restrict__ pidx,
                                                    const float* __restrict__ psum,
                                                    float* __restrict__ out1,
                                                    float* __restrict__ out2) {
    const int row = blockIdx.x;
    const int tid = threadIdx.x;
    const size_t base = (size_t)row * NT8;

    float m = -INFINITY, s = 0.f;
    int   id = 0x7fffffff;
    for (int c = tid; c < NT8; c += 256) {
        const float m2 = pmax[base + c];
        const int   i2 = pidx[base + c];
        const float s2 = psum[base + c];
        if (m2 > m || (m2 == m && m2 > -INFINITY && i2 < id)) {
            s = ((m > -INFINITY) ? s * exp2f((m - m2) * SC) : 0.f) + s2;
            m = m2; id = i2;
        } else if (m2 > -INFINITY) {
            s += s2 * exp2f((m2 - m) * SC);
        }
    }

    __shared__ float smax[256];
    __shared__ int   sidx[256];
    __shared__ float ssum[256];
    smax[tid] = m; sidx[tid] = id; ssum[tid] = s;
    __syncthreads();
#pragma unroll
    for (int off = 128; off > 0; off >>= 1) {
        if (tid < off) {
            const float m1 = smax[tid], m2 = smax[tid + off];
            const int   i1 = sidx[tid], i2 = sidx[tid + off];
            const float s1 = ssum[tid], s2 = ssum[tid + off];
            if (m2 > m1 || (m2 == m1 && m2 > -INFINITY && i2 < i1)) {
                smax[tid] = m2; sidx[tid] = i2;
                ssum[tid] = ((m1 > -INFINITY) ? s1 * exp2f((m1 - m2) * SC) : 0.f) + s2;
            } else if (m2 > -INFINITY) {
                ssum[tid] = s1 + s2 * exp2f((m2 - m1) * SC);
            }
        }
        __syncthreads();
    }
    if (tid == 0) {
        out2[row] = (float)sidx[0];
        out1[(size_t)row * Dd + 766] = smax[0];
        out1[(size_t)row * Dd + 767] = 1.0f / ssum[0];
    }
}

// ---------------------------------------------------------------------------
// Kernel 3: single-pass finalize (verified in R6/R7): read scores once, write
// probs + one-hot, gather W[pred], copy A row.
// ---------------------------------------------------------------------------
__global__ __launch_bounds__(256) void finalize_kernel(const float* __restrict__ A,
                                                       const float* __restrict__ W,
                                                       float* __restrict__ out0,
                                                       float* __restrict__ out1,
                                                       float* __restrict__ out2,
                                                       float* __restrict__ out3,
                                                       float* __restrict__ out4) {
    const int row = blockIdx.x;
    const int tid = threadIdx.x;
    float* srow = out4 + (size_t)row * Vv;
    float* hrow = out3 + (size_t)row * Vv;
    constexpr int NV4 = Vv >> 2;

    const float gmax = out1[(size_t)row * Dd + 766];
    const float inv  = out1[(size_t)row * Dd + 767];
    const int   pred = (int)out2[row];

    const float4* s4 = reinterpret_cast<const float4*>(srow);
    float4* p4 = reinterpret_cast<float4*>(srow);
    float4* h4 = reinterpret_cast<float4*>(hrow);
    for (int i = tid; i < NV4; i += 256) {
        const float4 v = s4[i];
        const int b = 4 * i;
        float4 p, h;
        p.x = exp2f((v.x - gmax) * SC) * inv;
        p.y = exp2f((v.y - gmax) * SC) * inv;
        p.z = exp2f((v.z - gmax) * SC) * inv;
        p.w = exp2f((v.w - gmax) * SC) * inv;
        h.x = (b + 0 == pred) ? 1.f : 0.f;
        h.y = (b + 1 == pred) ? 1.f : 0.f;
        h.z = (b + 2 == pred) ? 1.f : 0.f;
        h.w = (b + 3 == pred) ? 1.f : 0.f;
        p4[i] = p;
        h4[i] = h;
    }
    if (tid == 0) {
        const float val = srow[Vv - 1];
        srow[Vv - 1] = exp2f((val - gmax) * SC) * inv;
        hrow[Vv - 1] = (pred == Vv - 1) ? 1.f : 0.f;
    }

    __syncthreads();   // all threads have read the out1-tail stats stash

    const float4* wrow = reinterpret_cast<const float4*>(W + (size_t)pred * Dd);
    const float4* arow = reinterpret_cast<const float4*>(A + (size_t)row * Dd);
    float4* o0 = reinterpret_cast<float4*>(out0 + (size_t)row * Dd);
    float4* o1 = reinterpret_cast<float4*>(out1 + (size_t)row * Dd);
    if (tid < Dd / 4) {
        o0[tid] = wrow[tid];
        o1[tid] = arow[tid];   // overwrites the stats stash with the real copy
    }
}

}  // namespace

extern "C" void kernel_launch(void* const* d_in, const int* in_sizes, int n_in,
                              void* d_out, int out_size, void* d_ws, size_t ws_size,
                              hipStream_t stream) {
    const float* pred_embeds  = (const float*)d_in[0];   // (4,256,768)
    const float* embed_weight = (const float*)d_in[1];   // (50257,768)

    float* out  = (float*)d_out;
    float* out0 = out;                                    // (B,S,D)
    float* out1 = out0 + (size_t)Mm * Dd;                 // (B,S,D)
    float* out2 = out1 + (size_t)Mm * Dd;                 // (B,S)
    float* out3 = out2 + Mm;                              // (B,S,V) one-hot (scratch until finalize)
    float* out4 = out3 + (size_t)Mm * Vv;                 // (B,S,V) probs (scores until finalize)

    // packed scratch inside the out3 region
    _Float16* Whp = (_Float16*)out3;
    _Float16* Wlp = Whp + WPLANE;
    _Float16* Ahp = Wlp + WPLANE;
    _Float16* Alp = Ahp + APLANE;
    float*    tsq = (float*)(Alp + APLANE);
    float*    asq = tsq + Vv;                             // A row-sumsq (unused)
    float*    pmax = asq + Mm;
    int*      pidx = (int*)(pmax + (size_t)Mm * NT8);
    float*    psum = (float*)(pidx + (size_t)Mm * NT8);

    // zero the atomicAdd targets (tsq + asq contiguous)
    hipMemsetAsync(tsq, 0, (size_t)(Vv + Mm) * sizeof(float), stream);

    convert_pack_tsq<<<dim3(TW, 2), 256, 0, stream>>>(embed_weight, Whp, Wlp, tsq, Vv);
    convert_pack_tsq<<<dim3(TA, 2), 256, 0, stream>>>(pred_embeds, Ahp, Alp, asq, Mm);

    gemm_kernel<<<3200, 256, 0, stream>>>(Ahp, Alp, Whp, Wlp, tsq, out4,
                                          pmax, pidx, psum);

    reduce_stats<<<Mm, 256, 0, stream>>>(pmax, pidx, psum, out1, out2);

    finalize_kernel<<<Mm, 256, 0, stream>>>(pred_embeds, embed_weight,
                                            out0, out1, out2, out3, out4);
}

// Round 9
// 489.987 us; speedup vs baseline: 1.0983x; 1.0983x over previous
//
#include <hip/hip_runtime.h>
#include <math.h>

namespace {

constexpr int Bb = 4, Ss = 256, Dd = 768, Vv = 50257;
constexpr int Mm = Bb * Ss;               // 1024 rows
constexpr int BM = 128, BN = 128, BK = 32;
constexpr int NS = Dd / BK;               // 24 k-steps
constexpr int TW = (Vv + BN - 1) / BN;    // 393 W tiles (last padded w/ zeros)
constexpr int TA = Mm / BM;               // 8 A tiles
constexpr int NT2 = TW * 2;               // 786 per-row partial slices (64 cols each)
constexpr int CHUNK = BM * BK;            // 4096 f16 = 8 KB per (tile, step) per plane
constexpr float SC = 14.4269504088896341f;   // 10 * log2(e)

// LDS partial arrays: [128 rows][2 wc][17 fr-padded]  (pad kills bank conflicts)
constexpr int PSTRIDE = 17;
constexpr int PCOUNT  = 128 * 2 * PSTRIDE;         // 4352 entries per array
constexpr size_t SMEM_BYTES = (size_t)PCOUNT * 4 * 3;  // 52224 B > 32768 B staging

typedef _Float16 f16x8 __attribute__((ext_vector_type(8)));
typedef float f32x4 __attribute__((ext_vector_type(4)));

// Packed scratch layout (inside out3 region; finalize's one-hot overwrites it
// LAST — nothing reads scratch after finalize starts):
//   Whp, Wlp, Ahp, Alp, tsq[Vv], asq[Mm], pmax[Mm*NT2], pidx[Mm*NT2], psum[Mm*NT2]
constexpr size_t WPLANE = (size_t)TW * NS * CHUNK;   // 38,633,472 f16
constexpr size_t APLANE = (size_t)TA * NS * CHUNK;   //    786,432 f16
// bytes: 2*(WPLANE+APLANE)*2 + (Vv+Mm)*4 + 3*Mm*NT2*4 = ~167.5 MB < 205.8 MB

__device__ __forceinline__ void gload_lds16(const void* g, void* l) {
    typedef __attribute__((address_space(3))) void lds_t;
    typedef const __attribute__((address_space(1))) void gm_t;
    __builtin_amdgcn_global_load_lds((gm_t*)g, (lds_t*)l, 16, 0, 0);
}

// ---------------------------------------------------------------------------
// Kernel 1: fused split-convert + pack + row-sumsq (R5/R7-verified layout).
// ONE launch for both matrices: bx < TW -> W tile bx; else A tile (bx - TW).
// Thread: row = by*64 + (tid>>2), quarter q = tid&3 handles steps q*6..q*6+5.
// Rows >= nrows pack as zeros (kills GEMM bounds checks).
// ---------------------------------------------------------------------------
__global__ __launch_bounds__(256) void convert_pack_tsq(const float* __restrict__ srcW,
                                                        const float* __restrict__ srcA,
                                                        _Float16* __restrict__ Whp,
                                                        _Float16* __restrict__ Wlp,
                                                        _Float16* __restrict__ Ahp,
                                                        _Float16* __restrict__ Alp,
                                                        float* __restrict__ tsq,
                                                        float* __restrict__ asq) {
    const bool isW = blockIdx.x < TW;
    const int t    = isW ? blockIdx.x : (blockIdx.x - TW);
    const int nrows = isW ? Vv : Mm;
    const float* __restrict__ src = isW ? srcW : srcA;
    _Float16* __restrict__ hp = isW ? Whp : Ahp;
    _Float16* __restrict__ lp = isW ? Wlp : Alp;
    float* __restrict__ sumsq = isW ? tsq : asq;

    const int tid = threadIdx.x;
    const int r   = blockIdx.y * 64 + (tid >> 2);   // 0..127 tile row
    const int q   = tid & 3;                        // step quarter
    const int v   = t * BM + r;
    const bool valid = v < nrows;

    float sq = 0.f;
#pragma unroll
    for (int i = 0; i < 6; ++i) {
        const int s = q * 6 + i;
        float vals[32];
        if (valid) {
            const float4* p = reinterpret_cast<const float4*>(src + (size_t)v * Dd + s * BK);
#pragma unroll
            for (int k = 0; k < 8; ++k) *reinterpret_cast<float4*>(&vals[4 * k]) = p[k];
        } else {
#pragma unroll
            for (int k = 0; k < 32; ++k) vals[k] = 0.f;
        }
        const size_t chunk = ((size_t)t * NS + s) * CHUNK;
#pragma unroll
        for (int fq = 0; fq < 4; ++fq) {
            _Float16 hi8[8], lo8[8];
#pragma unroll
            for (int e = 0; e < 8; ++e) {
                const float x = vals[fq * 8 + e];
                sq = fmaf(x, x, sq);
                const _Float16 h = (_Float16)x;
                hi8[e] = h;
                lo8[e] = (_Float16)(x - (float)h);
            }
            *reinterpret_cast<f16x8*>(&hp[chunk + fq * (BM * 8) + (size_t)r * 8]) =
                *reinterpret_cast<const f16x8*>(hi8);
            *reinterpret_cast<f16x8*>(&lp[chunk + fq * (BM * 8) + (size_t)r * 8]) =
                *reinterpret_cast<const f16x8*>(lo8);
        }
    }
    sq += __shfl_xor(sq, 1);
    sq += __shfl_xor(sq, 2);
    if (valid && q == 0) sumsq[v] = sq;
}

// ---------------------------------------------------------------------------
// Kernel 2: scores = 2*(A.W^T) - tsq, packed split-f16 MFMA + XCD-chunked map.
// R7-verified: K-loop identical to R5 (250 us); epilogue emits per-(row,
// 64-col-slice) softmax partials via LDS merge (no shuffle chains).
// ---------------------------------------------------------------------------
__global__ __launch_bounds__(256) void gemm_kernel(const _Float16* __restrict__ Ahp,
                                                   const _Float16* __restrict__ Alp,
                                                   const _Float16* __restrict__ Whp,
                                                   const _Float16* __restrict__ Wlp,
                                                   const float* __restrict__ tsq,
                                                   float* __restrict__ scores,
                                                   float* __restrict__ pmax,
                                                   int*   __restrict__ pidx,
                                                   float* __restrict__ psum) {
    __shared__ __align__(16) char smem_raw[SMEM_BYTES];   // staging | partials (union)
    _Float16 (*lds)[CHUNK] = reinterpret_cast<_Float16(*)[CHUNK]>(smem_raw);

    const int b    = blockIdx.x;
    const int xcd  = b & 7;
    const int slot = b >> 3;
    const int tn   = xcd * 50 + (slot >> 3);   // contiguous tn chunk per XCD
    const int tm   = slot & 7;
    if (tn >= TW) return;

    const int tid  = threadIdx.x;
    const int wid  = tid >> 6;
    const int lane = tid & 63;
    const int wr   = wid >> 1;             // wave row (0..1)
    const int wc   = wid & 1;              // wave col (0..1)
    const int fr   = lane & 15;
    const int fq   = lane >> 4;

    const _Float16* gA_h = Ahp + (size_t)tm * NS * CHUNK;
    const _Float16* gA_l = Alp + (size_t)tm * NS * CHUNK;
    const _Float16* gW_h = Whp + (size_t)tn * NS * CHUNK;
    const _Float16* gW_l = Wlp + (size_t)tn * NS * CHUNK;

    f32x4 acc[4][4];
#pragma unroll
    for (int m = 0; m < 4; ++m)
#pragma unroll
        for (int n = 0; n < 4; ++n) acc[m][n] = (f32x4){0.f, 0.f, 0.f, 0.f};

    for (int s = 0; s < NS; ++s) {
        if (s) __syncthreads();
        const size_t so = (size_t)s * CHUNK;
        const _Float16* gsrc[4] = {gA_h + so, gA_l + so, gW_h + so, gW_l + so};
#pragma unroll
        for (int c = 0; c < 4; ++c) {
#pragma unroll
            for (int i = 0; i < 2; ++i) {
                const int seg = wid * 2 + i;              // 0..7, wave-uniform
                gload_lds16(gsrc[c] + seg * 512 + lane * 8, &lds[c][seg * 512]);
            }
        }
        __syncthreads();

        f16x8 ah[4], al[4];
#pragma unroll
        for (int m = 0; m < 4; ++m) {
            const int r = wr * 64 + m * 16 + fr;
            ah[m] = *reinterpret_cast<const f16x8*>(&lds[0][fq * (BM * 8) + r * 8]);
            al[m] = *reinterpret_cast<const f16x8*>(&lds[1][fq * (BM * 8) + r * 8]);
        }
#pragma unroll
        for (int n = 0; n < 4; ++n) {
            const int c = wc * 64 + n * 16 + fr;
            const f16x8 wh = *reinterpret_cast<const f16x8*>(&lds[2][fq * (BM * 8) + c * 8]);
            const f16x8 wl = *reinterpret_cast<const f16x8*>(&lds[3][fq * (BM * 8) + c * 8]);
#pragma unroll
            for (int m = 0; m < 4; ++m) {
                acc[m][n] = __builtin_amdgcn_mfma_f32_16x16x32_f16(ah[m], wh, acc[m][n], 0, 0, 0);
                acc[m][n] = __builtin_amdgcn_mfma_f32_16x16x32_f16(al[m], wh, acc[m][n], 0, 0, 0);
                acc[m][n] = __builtin_amdgcn_mfma_f32_16x16x32_f16(ah[m], wl, acc[m][n], 0, 0, 0);
            }
        }
    }

    // ------------- epilogue: score stores + LDS softmax partials -------------
    __syncthreads();                       // staging LDS dead -> reuse for partials
    float* pmL = reinterpret_cast<float*>(smem_raw);
    float* psL = pmL + PCOUNT;
    int*   piL = reinterpret_cast<int*>(psL + PCOUNT);

    float tq[4];
    int   gcol[4];
    bool  ok[4];
#pragma unroll
    for (int n = 0; n < 4; ++n) {
        gcol[n] = tn * BN + wc * 64 + n * 16 + fr;
        ok[n]   = gcol[n] < Vv;
        tq[n]   = ok[n] ? tsq[gcol[n]] : 0.f;
    }

#pragma unroll
    for (int m = 0; m < 4; ++m) {
#pragma unroll
        for (int r = 0; r < 4; ++r) {
            const int rloc = wr * 64 + m * 16 + fq * 4 + r;
            const int grow = tm * BM + rloc;
            // pass A: store scores + per-lane max/idx over the 4 n-values
            float vmax = -INFINITY;
            int   vidx = 0x7fffffff;
#pragma unroll
            for (int n = 0; n < 4; ++n) {
                if (ok[n]) {
                    const float sv = fmaf(2.f, acc[m][n][r], -tq[n]);
                    scores[(size_t)grow * Vv + gcol[n]] = sv;
                    if (sv > vmax) { vmax = sv; vidx = gcol[n]; }  // ascending gn
                }
            }
            // pass B: per-lane expsum relative to vmax
            float ls = 0.f;
#pragma unroll
            for (int n = 0; n < 4; ++n) {
                if (ok[n]) {
                    const float sv = fmaf(2.f, acc[m][n][r], -tq[n]);
                    ls += exp2f((sv - vmax) * SC);
                }
            }
            const int o = (rloc * 2 + wc) * PSTRIDE + fr;
            pmL[o] = vmax;
            psL[o] = ls;
            piL[o] = vidx;
        }
    }
    __syncthreads();

    // merge 16 fr-partials per (row, wc-slice); thread t -> (row=t>>1, wcs=t&1)
    {
        const int rloc = tid >> 1;
        const int wcs  = tid & 1;
        float m = -INFINITY, s = 0.f;
        int   id = 0x7fffffff;
#pragma unroll
        for (int f = 0; f < 16; ++f) {
            const int o = (rloc * 2 + wcs) * PSTRIDE + f;
            const float m2 = pmL[o];
            const int   i2 = piL[o];
            const float s2 = psL[o];
            if (m2 > m || (m2 == m && i2 < id)) {
                s = ((m > -INFINITY) ? s * exp2f((m - m2) * SC) : 0.f) + s2;
                m = m2; id = i2;
            } else {
                s += s2 * exp2f((m2 - m) * SC);
            }
        }
        const int grow = tm * BM + rloc;
        const int cidx = tn * 2 + wcs;
        const size_t o = (size_t)grow * NT2 + cidx;
        pmax[o] = m;
        pidx[o] = id;
        psum[o] = s;
    }
}

// ---------------------------------------------------------------------------
// Kernel 2b: merge 786 partials per row -> pred (out2), (gmax, inv) stashed in
// the tail of out1's row (verified in R6/R7).
// ---------------------------------------------------------------------------
__global__ __launch_bounds__(256) void reduce_stats(const float* __restrict__ pmax,
                                                    const int*   __restrict__ pidx,
                                                    const float* __restrict__ psum,
                                                    float* __restrict__ out1,
                                                    float* __restrict__ out2) {
    const int row = blockIdx.x;
    const int tid = threadIdx.x;
    const size_t base = (size_t)row * NT2;

    float m = -INFINITY, s = 0.f;
    int   id = 0x7fffffff;
    for (int c = tid; c < NT2; c += 256) {
        const float m2 = pmax[base + c];
        const int   i2 = pidx[base + c];
        const float s2 = psum[base + c];
        if (m2 > m || (m2 == m && i2 < id)) {
            s = ((m > -INFINITY) ? s * exp2f((m - m2) * SC) : 0.f) + s2;
            m = m2; id = i2;
        } else {
            s += (m2 > -INFINITY) ? s2 * exp2f((m2 - m) * SC) : 0.f;
        }
    }

    __shared__ float smax[256];
    __shared__ int   sidx[256];
    __shared__ float ssum[256];
    smax[tid] = m; sidx[tid] = id; ssum[tid] = s;
    __syncthreads();
#pragma unroll
    for (int off = 128; off > 0; off >>= 1) {
        if (tid < off) {
            const float m1 = smax[tid], m2 = smax[tid + off];
            const int   i1 = sidx[tid], i2 = sidx[tid + off];
            const float s1 = ssum[tid], s2 = ssum[tid + off];
            if (m2 > m1 || (m2 == m1 && i2 < i1)) {
                smax[tid] = m2; sidx[tid] = i2;
                ssum[tid] = ((m1 > -INFINITY) ? s1 * exp2f((m1 - m2) * SC) : 0.f) + s2;
            } else {
                ssum[tid] = s1 + ((m2 > -INFINITY) ? s2 * exp2f((m2 - m1) * SC) : 0.f);
            }
        }
        __syncthreads();
    }
    if (tid == 0) {
        out2[row] = (float)sidx[0];
        out1[(size_t)row * Dd + 766] = smax[0];
        out1[(size_t)row * Dd + 767] = 1.0f / ssum[0];
    }
}

// ---------------------------------------------------------------------------
// Kernel 3: single-pass finalize (verified in R6/R7): read scores once, write
// probs + one-hot, gather W[pred], copy A row.
// ---------------------------------------------------------------------------
__global__ __launch_bounds__(256) void finalize_kernel(const float* __restrict__ A,
                                                       const float* __restrict__ W,
                                                       float* __restrict__ out0,
                                                       float* __restrict__ out1,
                                                       float* __restrict__ out2,
                                                       float* __restrict__ out3,
                                                       float* __restrict__ out4) {
    const int row = blockIdx.x;
    const int tid = threadIdx.x;
    float* srow = out4 + (size_t)row * Vv;
    float* hrow = out3 + (size_t)row * Vv;
    constexpr int NV4 = Vv >> 2;

    const float gmax = out1[(size_t)row * Dd + 766];
    const float inv  = out1[(size_t)row * Dd + 767];
    const int   pred = (int)out2[row];

    const float4* s4 = reinterpret_cast<const float4*>(srow);
    float4* p4 = reinterpret_cast<float4*>(srow);
    float4* h4 = reinterpret_cast<float4*>(hrow);
    for (int i = tid; i < NV4; i += 256) {
        const float4 v = s4[i];
        const int b = 4 * i;
        float4 p, h;
        p.x = exp2f((v.x - gmax) * SC) * inv;
        p.y = exp2f((v.y - gmax) * SC) * inv;
        p.z = exp2f((v.z - gmax) * SC) * inv;
        p.w = exp2f((v.w - gmax) * SC) * inv;
        h.x = (b + 0 == pred) ? 1.f : 0.f;
        h.y = (b + 1 == pred) ? 1.f : 0.f;
        h.z = (b + 2 == pred) ? 1.f : 0.f;
        h.w = (b + 3 == pred) ? 1.f : 0.f;
        p4[i] = p;
        h4[i] = h;
    }
    if (tid == 0) {
        const float val = srow[Vv - 1];
        srow[Vv - 1] = exp2f((val - gmax) * SC) * inv;
        hrow[Vv - 1] = (pred == Vv - 1) ? 1.f : 0.f;
    }

    __syncthreads();   // all threads have read the out1-tail stats stash

    const float4* wrow = reinterpret_cast<const float4*>(W + (size_t)pred * Dd);
    const float4* arow = reinterpret_cast<const float4*>(A + (size_t)row * Dd);
    float4* o0 = reinterpret_cast<float4*>(out0 + (size_t)row * Dd);
    float4* o1 = reinterpret_cast<float4*>(out1 + (size_t)row * Dd);
    if (tid < Dd / 4) {
        o0[tid] = wrow[tid];
        o1[tid] = arow[tid];   // overwrites the stats stash with the real copy
    }
}

}  // namespace

extern "C" void kernel_launch(void* const* d_in, const int* in_sizes, int n_in,
                              void* d_out, int out_size, void* d_ws, size_t ws_size,
                              hipStream_t stream) {
    const float* pred_embeds  = (const float*)d_in[0];   // (4,256,768)
    const float* embed_weight = (const float*)d_in[1];   // (50257,768)

    float* out  = (float*)d_out;
    float* out0 = out;                                    // (B,S,D)
    float* out1 = out0 + (size_t)Mm * Dd;                 // (B,S,D)
    float* out2 = out1 + (size_t)Mm * Dd;                 // (B,S)
    float* out3 = out2 + Mm;                              // (B,S,V) one-hot (scratch until finalize)
    float* out4 = out3 + (size_t)Mm * Vv;                 // (B,S,V) probs (scores until finalize)

    // packed scratch inside the out3 region
    _Float16* Whp = (_Float16*)out3;
    _Float16* Wlp = Whp + WPLANE;
    _Float16* Ahp = Wlp + WPLANE;
    _Float16* Alp = Ahp + APLANE;
    float*    tsq = (float*)(Alp + APLANE);
    float*    asq = tsq + Vv;                             // A row-sumsq (unused)
    float*    pmax = asq + Mm;
    int*      pidx = (int*)(pmax + (size_t)Mm * NT2);
    float*    psum = (float*)(pidx + (size_t)Mm * NT2);

    convert_pack_tsq<<<dim3(TW + TA, 2), 256, 0, stream>>>(embed_weight, pred_embeds,
                                                           Whp, Wlp, Ahp, Alp, tsq, asq);

    gemm_kernel<<<3200, 256, 0, stream>>>(Ahp, Alp, Whp, Wlp, tsq, out4,
                                          pmax, pidx, psum);

    reduce_stats<<<Mm, 256, 0, stream>>>(pmax, pidx, psum, out1, out2);

    finalize_kernel<<<Mm, 256, 0, stream>>>(pred_embeds, embed_weight,
                                            out0, out1, out2, out3, out4);
}